// Round 1
// 404.590 us; speedup vs baseline: 1.0971x; 1.0971x over previous
//
#include <hip/hip_runtime.h>
#include <hip/hip_bf16.h>
#include <math.h>

typedef __bf16 bf16_t;
typedef bf16_t bf16x8 __attribute__((ext_vector_type(8)));
typedef bf16_t bf16x4 __attribute__((ext_vector_type(4)));
typedef float f32x4 __attribute__((ext_vector_type(4)));

#define WAYS 5
#define SHOTS 5
#define F_DIM 1024
#define HID 512
#define BATCH 2048
#define NN 26
#define NC 6
#define MROWS (BATCH * NC)   // 12288

#define S1 (HID * F_DIM)     // w1: 524288
#define S2 (HID * HID)       // w2: 262144
#define S3 (F_DIM * HID)     // w3: 524288
#define CVT_BLOCKS ((S1 + S2 + S3) / 512)   // 2560 blocks of 128 thr * 4 elems

// ---- prep: fused weight f32->bf16 convert + nf compaction (means + query) ----
__global__ __launch_bounds__(128)
void prep_kernel(const float* __restrict__ node,
                 const float* __restrict__ w1, const float* __restrict__ w2,
                 const float* __restrict__ w3, bf16_t* __restrict__ wall,
                 bf16_t* __restrict__ nfc_b) {
    if (blockIdx.x < CVT_BLOCKS) {
        int i = (blockIdx.x * 128 + threadIdx.x) * 4;
        const float* src;
        int j = i;
        if (i < S1)            { src = w1; }
        else if (i < S1 + S2)  { src = w2; j = i - S1; }
        else                   { src = w3; j = i - S1 - S2; }
        float4 v = *(const float4*)(src + j);
        bf16x4 o;
        o[0] = (bf16_t)v.x; o[1] = (bf16_t)v.y; o[2] = (bf16_t)v.z; o[3] = (bf16_t)v.w;
        *(bf16x4*)(wall + i) = o;
        return;
    }
    int row = blockIdx.x - CVT_BLOCKS;   // b*6 + w
    int b = row / NC;
    int w = row - b * NC;
    int f = threadIdx.x * 8;
    const float* src = node + (size_t)b * NN * F_DIM;
    float acc[8];
    if (w < WAYS) {
        #pragma unroll
        for (int e = 0; e < 8; ++e) acc[e] = 0.f;
        #pragma unroll
        for (int s = 0; s < SHOTS; ++s) {
            const float* r = src + (size_t)(w * SHOTS + s) * F_DIM + f;
            float4 v0 = *(const float4*)r;
            float4 v1 = *(const float4*)(r + 4);
            acc[0] += v0.x; acc[1] += v0.y; acc[2] += v0.z; acc[3] += v0.w;
            acc[4] += v1.x; acc[5] += v1.y; acc[6] += v1.z; acc[7] += v1.w;
        }
        #pragma unroll
        for (int e = 0; e < 8; ++e) acc[e] *= 0.2f;
    } else {
        const float* r = src + (size_t)25 * F_DIM + f;
        float4 v0 = *(const float4*)r;
        float4 v1 = *(const float4*)(r + 4);
        acc[0] = v0.x; acc[1] = v0.y; acc[2] = v0.z; acc[3] = v0.w;
        acc[4] = v1.x; acc[5] = v1.y; acc[6] = v1.z; acc[7] = v1.w;
    }
    bf16x8 ob;
    #pragma unroll
    for (int e = 0; e < 8; ++e) ob[e] = (bf16_t)acc[e];
    *(bf16x8*)(nfc_b + (size_t)row * F_DIM + f) = ob;
}

// -------- GEMM: C[M,N] = A[M,K] @ W[N,K]^T, tile 128 x TN, 2-phase dbuf --------
// EPI 0: y = lrelu(acc*s + t)  s = g*rsqrt(v+eps), t = (b-m)*s + be
// EPI 1: y = sigmoid(acc + b)
template<int EPI, int TN>
__global__ __launch_bounds__(256)
void gemm_bt(const bf16_t* __restrict__ A, const bf16_t* __restrict__ W,
             bf16_t* __restrict__ C, int M, int N, int K,
             const float* __restrict__ bias, const float* __restrict__ gam,
             const float* __restrict__ bet, const float* __restrict__ mu,
             const float* __restrict__ var) {
    constexpr int NI = TN / 32;          // 16-col tiles per wave
    __shared__ bf16_t As[2][128 * 32];
    __shared__ bf16_t Bs[2][TN * 32];
    const int tid = threadIdx.x;
    const int lane = tid & 63, wid = tid >> 6;

    // T1: bijective XCD swizzle. nwg = 768 (multiple of 8), gridDim.x = 8.
    const int nwg = gridDim.x * gridDim.y;
    const int orig = blockIdx.y * gridDim.x + blockIdx.x;
    const int wg = (orig & 7) * (nwg >> 3) + (orig >> 3);
    const int bxi = wg & (gridDim.x - 1);
    const int byi = wg / gridDim.x;
    const int bm = byi * 128, bn = bxi * TN;

    const int l15 = lane & 15, quad = lane >> 4;
    const int wm = (wid & 1) * 64, wn = (wid >> 1) * (TN / 2);

    // staging geometry: A 128 rows (2 issues/wave), B TN rows (TN/64 issues/wave)
    const int srowA = wid * 32;
    const int srowB = wid * (TN / 4);
    const int lrow = lane >> 2;          // 0..15
    const int lcol = (lane & 3) * 8;     // bf16 elements
    const bf16_t* gA = A + (size_t)(bm + srowA + lrow) * K + lcol;
    const bf16_t* gB = W + (size_t)(bn + srowB + lrow) * K + lcol;

    f32x4 acc[4][NI] = {};

    auto stage = [&](int buf, int k0) {
        bf16_t* lA = &As[buf][srowA * 32];
        bf16_t* lB = &Bs[buf][srowB * 32];
        #pragma unroll
        for (int q = 0; q < 2; ++q)
            __builtin_amdgcn_global_load_lds(
                (const __attribute__((address_space(1))) void*)(gA + (size_t)q * 16 * K + k0),
                (__attribute__((address_space(3))) void*)(lA + q * 16 * 32), 16, 0, 0);
        #pragma unroll
        for (int q = 0; q < TN / 64; ++q)
            __builtin_amdgcn_global_load_lds(
                (const __attribute__((address_space(1))) void*)(gB + (size_t)q * 16 * K + k0),
                (__attribute__((address_space(3))) void*)(lB + q * 16 * 32), 16, 0, 0);
    };

    stage(0, 0);
    __syncthreads();                      // drains vmcnt(0): buf0 ready
    int cur = 0;
    for (int k0 = 0; k0 < K; k0 += 32) {
        if (k0 + 32 < K) stage(cur ^ 1, k0 + 32);   // next tile in flight
        bf16x8 af[4], bfr[NI];
        #pragma unroll
        for (int mi = 0; mi < 4; ++mi)
            af[mi] = *(const bf16x8*)&As[cur][(wm + mi * 16 + l15) * 32 + quad * 8];
        #pragma unroll
        for (int ni = 0; ni < NI; ++ni)
            bfr[ni] = *(const bf16x8*)&Bs[cur][(wn + ni * 16 + l15) * 32 + quad * 8];
        #pragma unroll
        for (int mi = 0; mi < 4; ++mi)
            #pragma unroll
            for (int ni = 0; ni < NI; ++ni)
                acc[mi][ni] = __builtin_amdgcn_mfma_f32_16x16x32_bf16(af[mi], bfr[ni], acc[mi][ni], 0, 0, 0);
        __syncthreads();                  // vmcnt(0) drain now hidden under compute
        cur ^= 1;
    }

    #pragma unroll
    for (int ni = 0; ni < NI; ++ni) {
        const int n = bn + wn + ni * 16 + l15;
        float s, t;
        if constexpr (EPI == 0) {
            float sg = gam[n] * rsqrtf(var[n] + 1e-5f);
            s = sg;
            t = (bias[n] - mu[n]) * sg + bet[n];
        } else {
            s = 1.0f;
            t = bias[n];
        }
        #pragma unroll
        for (int mi = 0; mi < 4; ++mi) {
            const int m = bm + wm + mi * 16 + quad * 4;
            #pragma unroll
            for (int r = 0; r < 4; ++r) {
                float y = acc[mi][ni][r] * s + t;
                if constexpr (EPI == 0) {
                    y = y > 0.0f ? y : 0.01f * y;
                } else {
                    y = 1.0f / (1.0f + __expf(-y));
                }
                C[(size_t)(m + r) * N + n] = (bf16_t)y;
            }
        }
    }
}

// ------- sim: per-episode 6x6 sims, direct global bf16x8 reads (no big LDS) -------
__global__ __launch_bounds__(256)
void sim_kernel(const bf16_t* __restrict__ nfc, const bf16_t* __restrict__ att,
                float* __restrict__ out) {
    __shared__ float dmat[NC * NC], n2mat[NC * NC], simc[NC * NC];
    const int b = blockIdx.x, tid = threadIdx.x;
    const bf16_t* xs = nfc + (size_t)b * NC * F_DIM;
    const bf16_t* as = att + (size_t)b * NC * F_DIM;
    const int lane = tid & 63, wid = tid >> 6;
    for (int t = wid; t < 21; t += 4) {
        // upper-triangle (incl diag) pair index -> (i,j), no scratch arrays
        const int i = (t >= 6) + (t >= 11) + (t >= 15) + (t >= 18) + (t >= 20);
        const int j = t - (i * (13 - i)) / 2 + i;
        float d = 0.f, qij = 0.f, qji = 0.f;
        #pragma unroll
        for (int c = 0; c < 2; ++c) {
            const int f0 = lane * 8 + c * 512;
            bf16x8 vai = *(const bf16x8*)&as[i * F_DIM + f0];
            bf16x8 vaj = *(const bf16x8*)&as[j * F_DIM + f0];
            bf16x8 vxi = *(const bf16x8*)&xs[i * F_DIM + f0];
            bf16x8 vxj = *(const bf16x8*)&xs[j * F_DIM + f0];
            #pragma unroll
            for (int e = 0; e < 8; ++e) {
                float ai = (float)vai[e], aj = (float)vaj[e];
                float xi = (float)vxi[e], xj = (float)vxj[e];
                float a2i = ai * ai, a2j = aj * aj;
                float pi = a2i * xi, pj = a2j * xj;
                d   += pi * pj;        // dot(P_i, P_j)
                qij += pi * xi * a2j;  // n2[i][j]
                qji += pj * xj * a2i;  // n2[j][i]
            }
        }
        #pragma unroll
        for (int off = 32; off > 0; off >>= 1) {
            d   += __shfl_xor(d, off);
            qij += __shfl_xor(qij, off);
            qji += __shfl_xor(qji, off);
        }
        if (lane == 0) {
            dmat[i * NC + j] = d; dmat[j * NC + i] = d;
            n2mat[i * NC + j] = qij; n2mat[j * NC + i] = qji;
        }
    }
    __syncthreads();
    if (tid < NC * NC) {
        int i = tid / NC, j = tid - (tid / NC) * NC;
        simc[tid] = dmat[tid] / sqrtf(n2mat[i * NC + j] * n2mat[j * NC + i]);
    }
    __syncthreads();
    float* o = out + (size_t)b * (2 * NN * NN);
    for (int e = tid; e < 2 * NN * NN; e += 256) {
        int ch = e / (NN * NN);
        int rem = e - ch * (NN * NN);
        int i = rem / NN, j = rem - (rem / NN) * NN;
        float s = simc[(i / 5) * NC + (j / 5)];
        float v = ch ? 1.0f - s : s;
        v = fminf(fmaxf(v, 0.0f), 1.0f);
        o[e] = v;
    }
}

extern "C" void kernel_launch(void* const* d_in, const int* in_sizes, int n_in,
                              void* d_out, int out_size, void* d_ws, size_t ws_size,
                              hipStream_t stream) {
    const float* node = (const float*)d_in[0];
    const float* w1  = (const float*)d_in[1];
    const float* b1  = (const float*)d_in[2];
    const float* g1  = (const float*)d_in[3];
    const float* be1 = (const float*)d_in[4];
    const float* m1  = (const float*)d_in[5];
    const float* v1  = (const float*)d_in[6];
    const float* w2  = (const float*)d_in[7];
    const float* b2  = (const float*)d_in[8];
    const float* g2  = (const float*)d_in[9];
    const float* be2 = (const float*)d_in[10];
    const float* m2  = (const float*)d_in[11];
    const float* v2  = (const float*)d_in[12];
    const float* w3  = (const float*)d_in[13];
    const float* b3  = (const float*)d_in[14];
    float* out = (float*)d_out;

    char* ws = (char*)d_ws;
    size_t off = 0;
    bf16_t* wall  = (bf16_t*)(ws + off); off += (size_t)(S1 + S2 + S3) * 2;   // 2.62 MB
    bf16_t* w1b = wall, *w2b = wall + S1, *w3b = wall + S1 + S2;
    bf16_t* nfc_b = (bf16_t*)(ws + off); off += (size_t)MROWS * F_DIM * 2;    // 25.2 MB
    bf16_t* x1    = (bf16_t*)(ws + off); off += (size_t)MROWS * HID * 2;      // 12.6 MB
    bf16_t* x2    = (bf16_t*)(ws + off); off += (size_t)MROWS * HID * 2;      // 12.6 MB
    bf16_t* attb  = (bf16_t*)(ws + off); off += (size_t)MROWS * F_DIM * 2;    // 25.2 MB

    prep_kernel<<<CVT_BLOCKS + MROWS, 128, 0, stream>>>(node, w1, w2, w3, wall, nfc_b);
    gemm_bt<0, 64><<<dim3(HID / 64, MROWS / 128), 256, 0, stream>>>(
        nfc_b, w1b, x1, MROWS, HID, F_DIM, b1, g1, be1, m1, v1);
    gemm_bt<0, 64><<<dim3(HID / 64, MROWS / 128), 256, 0, stream>>>(
        x1, w2b, x2, MROWS, HID, HID, b2, g2, be2, m2, v2);
    gemm_bt<1, 128><<<dim3(F_DIM / 128, MROWS / 128), 256, 0, stream>>>(
        x2, w3b, attb, MROWS, F_DIM, HID, b3, nullptr, nullptr, nullptr, nullptr);
    sim_kernel<<<BATCH, 256, 0, stream>>>(nfc_b, attb, out);
}